// Round 5
// baseline (863.929 us; speedup 1.0000x reference)
//
#include <hip/hip_runtime.h>
#include <hip/hip_bf16.h>

// HypConvHyperboloid: B=32,H=64,W=64, C_IN=65, 3x3 edge-pad conv -> HCat(577) -> Lorentz FC(255) -> time restore
// M = 131072 pixels, K = 576 (bf16 MFMA) + 1 (t_cat fp32 rank-1 in epilogue), N = 255 (pad 256)
// Round 10: occupancy is THE variable (R5 24waves=90 < R7/R9 16waves=98/113 < R8 8waves=122; perf
//           tracks resident waves monotonically; all pipes <20% busy -> latency-bound, TLP-hidden).
//           Change vs R5 (champion, verbatim otherwise): A-operand moved out of LDS entirely —
//           A-frags read per-wave directly from xs (L2/L1-hot, wave-uniform y-neighbor, static
//           clamped x) as global_load_dwordx4. LDS = B-dbuf 32KB + tc 512B = 33.8KB ->
//           4 blocks/CU = 32 waves/CU (HW thread cap), 1024 blocks all co-resident (no tail).
//           Barrier drain now covers only 2 L2-hot B gl2lds. K-loop fully unrolled (static dy/dx/clamp).

#define CLAMP63(v) ((v) < 0 ? 0 : ((v) > 63 ? 63 : (v)))

typedef __attribute__((ext_vector_type(8))) short short8;   // 8 bf16 = 4 VGPRs
typedef __attribute__((ext_vector_type(4))) float floatx4;  // C/D frag

__device__ __forceinline__ void gl2lds16(const void* g, void* l) {
  __builtin_amdgcn_global_load_lds(
      (const __attribute__((address_space(1))) void*)g,
      (__attribute__((address_space(3))) void*)l, 16, 0, 0);
}

// ---- prep: x spatial -> bf16 pixel-major [pix][64] (16B stores); col0 -> tsq = t^2
__global__ void prep_x(const float* __restrict__ x, __hip_bfloat16* __restrict__ xs,
                       float* __restrict__ tsq) {
  int idx = blockIdx.x * 256 + threadIdx.x;   // 1048576 = 131072 pix * 8 groups
  int p = idx >> 3, g = idx & 7;
  const float* src = x + (size_t)p * 65 + 1 + g * 8;
  __align__(16) __hip_bfloat16 tmp[8];
#pragma unroll
  for (int i = 0; i < 8; ++i) tmp[i] = __float2bfloat16(src[i]);
  *(short8*)(xs + (size_t)idx * 8) = *(const short8*)tmp;
  if (g == 0) { float t = x[(size_t)p * 65]; tsq[p] = t * t; }  // same cacheline as cols 1..8
}

// ---- prep: W spatial cols -> bf16 n-major [256][576] (row 255 zero); W col0 + b -> fp32 padded
__global__ void prep_w(const float* __restrict__ W, const float* __restrict__ b,
                       __hip_bfloat16* __restrict__ Wb, float* __restrict__ Wt0,
                       float* __restrict__ bp) {
  int n = blockIdx.x;  // 256
  for (int k = threadIdx.x; k < 576; k += 256)
    Wb[n * 576 + k] = __float2bfloat16((n < 255) ? W[n * 577 + 1 + k] : 0.f);
  if (threadIdx.x == 0) {
    Wt0[n] = (n < 255) ? W[n * 577] : 0.f;
    bp[n]  = (n < 255) ? b[n] : 0.f;
  }
}

// B staging for iteration IT, buffer BUF (2 chunks/wave; dests wave-uniform; R5-proven, 0 conflicts)
#define STAGE_B(IT, BUF)                                                        \
  do {                                                                          \
    _Pragma("unroll")                                                           \
    for (int j_ = 0; j_ < 2; ++j_)                                              \
      gl2lds16(b_src[j_] + (IT) * 32, Bb + (BUF) * 8192 + (w * 2 + j_) * 512);  \
  } while (0)

// ---- main: M=128 x N=256 per block, BK=32, 18 iters, 8 waves (each 64x64).
// LDS: tc [0,512) | B dbuf [512, 33280+512) ; epilogue zbuf reuses [512, 33792) stride 260.
// A-frags: direct global reads from xs (no LDS, no barrier coupling).
__launch_bounds__(512, 8)
__global__ void hypconv_main(const float* __restrict__ tsq,
                             const __hip_bfloat16* __restrict__ xs,
                             const __hip_bfloat16* __restrict__ Wb,
                             const float* __restrict__ Wt0,
                             const float* __restrict__ bp,
                             float* __restrict__ out) {
  __shared__ __align__(16) char smem[33792];
  float* tc_lds = (float*)smem;               // 128 f32
  ushort* Bb = (ushort*)(smem + 512);         // 2 x 8192 ushort
  float* zbuf = (float*)(smem + 512);         // 32 rows x 260 f32 = 33280 B (post-loop reuse)

  const int tid = threadIdx.x;
  const int w = tid >> 6, lane = tid & 63;
  const int quad = lane >> 4, ln = lane & 15;

  // XCD swizzle: 1024 blocks, 128-chunk per XCD (bijective); all 1024 co-resident (4 blocks/CU)
  const int mb = ((blockIdx.x & 7) << 7) + (blockIdx.x >> 3);
  const int pix_base = mb * 128;
  const int m_off = (w >> 2) * 64, n_off = (w & 3) * 64;

  // A geometry: wave's 64 m-rows live in ONE image row -> y-neighbor is wave-uniform.
  const int bb = mb >> 5;                       // image (4096 pix), 128 pix per block = 2 rows
  const int a_by = ((mb & 31) << 1) + (w >> 2); // this wave's image row
  // per-(mf,dx) clamped x: bx = mf*16 + ln
  int a_px[4][3];                               // element offset (x2 + bb*4096)*64, sans y-term
#pragma unroll
  for (int mf = 0; mf < 4; ++mf)
#pragma unroll
    for (int dxi = 0; dxi < 3; ++dxi) {
      int x2 = CLAMP63(mf * 16 + ln + dxi - 1);
      a_px[mf][dxi] = ((bb << 12) + x2) << 6;
    }

  // B chunks j=0,1: chunk c = w*2+j -> n = (c&3)*64+lane, k-group = c>>2
  const __hip_bfloat16* b_src[2];
#pragma unroll
  for (int j = 0; j < 2; ++j) {
    int c = w * 2 + j;
    b_src[j] = Wb + (size_t)((c & 3) * 64 + lane) * 576 + (c >> 2) * 8;
  }

  floatx4 acc[4][4];
#pragma unroll
  for (int mf = 0; mf < 4; ++mf)
#pragma unroll
    for (int nf = 0; nf < 4; ++nf)
      acc[mf][nf] = (floatx4){0.f, 0.f, 0.f, 0.f};

  STAGE_B(0, 0);  // prologue loads in flight

  // t_cat from tsq (512 KB, L2-resident)
  if (tid < 128) {
    int pix = pix_base + tid;
    int bx = pix & 63, by = (pix >> 6) & 63, bb2 = pix >> 12;
    float s = 0.f;
#pragma unroll
    for (int dy = -1; dy <= 1; ++dy) {
      int y2 = CLAMP63(by + dy);
#pragma unroll
      for (int dx = -1; dx <= 1; ++dx) {
        int x2 = CLAMP63(bx + dx);
        s += tsq[(bb2 * 64 + y2) * 64 + x2];
      }
    }
    tc_lds[tid] = sqrtf(s - 8.0f);
  }

#pragma unroll
  for (int it = 0; it < 18; ++it) {
    __syncthreads();                 // Bb(it&1) ready; prev frag reads done
    if (it < 17) STAGE_B(it + 1, (it + 1) & 1);   // prefetch overlaps frag reads + MFMA
    const int nbr = it >> 1;                       // compile-time (full unroll)
    const int dy = nbr / 3 - 1, dxi = nbr % 3;
    const int y2 = CLAMP63(a_by + dy);             // wave-uniform
    const int kofs = (it & 1) * 32 + quad * 8;     // channel slice of this frag
    const ushort* Br = Bb + (it & 1) * 8192;
    short8 af[4], bfr[4];
#pragma unroll
    for (int mf = 0; mf < 4; ++mf)
      af[mf] = *(const short8*)(xs + (size_t)(a_px[mf][dxi] + (y2 << 12) + kofs));
#pragma unroll
    for (int nf = 0; nf < 4; ++nf)
      bfr[nf] = *(const short8*)&Br[(quad * 256 + n_off + nf * 16 + ln) * 8];
#pragma unroll
    for (int mf = 0; mf < 4; ++mf)
#pragma unroll
      for (int nf = 0; nf < 4; ++nf)
        acc[mf][nf] = __builtin_amdgcn_mfma_f32_16x16x32_bf16(af[mf], bfr[nf], acc[mf][nf], 0, 0, 0);
  }

  // ---- epilogue: z = acc + b[n] + t_cat[m]*W0[n]; LDS-staged (stride 260), 1KB-row flush (R5 verbatim)
  __syncthreads();
  float wn[4], bnv[4];
#pragma unroll
  for (int nf = 0; nf < 4; ++nf) {
    int n = n_off + nf * 16 + ln;
    wn[nf] = Wt0[n];
    bnv[nf] = bp[n];
  }

#pragma unroll
  for (int mf = 0; mf < 4; ++mf) {
    // stage 32 rows: lr = (w>>2)*16 + quad*4 + r ; col = (1+n)&255 (z[255]=0 by padding)
#pragma unroll
    for (int r = 0; r < 4; ++r) {
      float tcv = tc_lds[m_off + mf * 16 + quad * 4 + r];
      int lr = (w >> 2) * 16 + quad * 4 + r;
#pragma unroll
      for (int nf = 0; nf < 4; ++nf) {
        float z = acc[mf][nf][r] + bnv[nf] + tcv * wn[nf];
        zbuf[lr * 260 + ((1 + n_off + nf * 16 + ln) & 255)] = z;
      }
    }
    __syncthreads();
    // flush: 8 waves x 4 rows; sum(z^2) 64-lane butterfly; t_out -> col 0
#pragma unroll
    for (int rr = 0; rr < 4; ++rr) {
      int lr = w * 4 + rr;
      float4 v = *(const float4*)&zbuf[lr * 260 + lane * 4];
      float ss = v.x * v.x + v.y * v.y + v.z * v.z + v.w * v.w;  // col0 holds z[255]=0
      ss += __shfl_xor(ss, 1, 64);
      ss += __shfl_xor(ss, 2, 64);
      ss += __shfl_xor(ss, 4, 64);
      ss += __shfl_xor(ss, 8, 64);
      ss += __shfl_xor(ss, 16, 64);
      ss += __shfl_xor(ss, 32, 64);
      float tout = sqrtf(1.0f + ss);
      if (lane == 0) v.x = tout;
      int m = (lr >> 4) * 64 + mf * 16 + (lr & 15);
      *(float4*)&out[(size_t)(pix_base + m) * 256 + lane * 4] = v;
    }
    if (mf < 3) __syncthreads();  // protect zbuf before next chunk's staging
  }
}

extern "C" void kernel_launch(void* const* d_in, const int* in_sizes, int n_in,
                              void* d_out, int out_size, void* d_ws, size_t ws_size,
                              hipStream_t stream) {
  const float* x = (const float*)d_in[0];   // (32,64,64,65)
  const float* W = (const float*)d_in[1];   // (255,577)
  const float* b = (const float*)d_in[2];   // (255,)
  float* out = (float*)d_out;               // (32,64,64,256)
  char* ws = (char*)d_ws;

  // workspace: xs 16,777,216 | Wb 294,912 | Wt0 1K | bp 1K | tsq 524,288  (~17.6 MB)
  __hip_bfloat16* xs  = (__hip_bfloat16*)(ws);
  __hip_bfloat16* Wb  = (__hip_bfloat16*)(ws + 16777216);
  float*          Wt0 = (float*)(ws + 17072128);
  float*          bp  = (float*)(ws + 17073152);
  float*          tsq = (float*)(ws + 17074176);

  prep_x<<<4096, 256, 0, stream>>>(x, xs, tsq);
  prep_w<<<256,  256, 0, stream>>>(W, b, Wb, Wt0, bp);
  hypconv_main<<<1024, 512, 0, stream>>>(tsq, xs, Wb, Wt0, bp, out);
}

// Round 7
// 307.029 us; speedup vs baseline: 2.8138x; 2.8138x over previous
//
#include <hip/hip_runtime.h>
#include <hip/hip_bf16.h>

// HypConvHyperboloid: B=32,H=64,W=64, C_IN=65, 3x3 edge-pad conv -> HCat(577) -> Lorentz FC(255) -> time restore
// M = 131072 pixels, K = 576 (bf16 MFMA) + 1 (t_cat fp32 rank-1 in epilogue), N = 255 (pad 256)
// Round 12: RESUBMIT of R11 (round-6 bench died in infra: "container failed twice"; no counters).
//           BARRIER-FREE K-loop. Evidence: every barrier-coupled variant (R5-R9) lands 88-122us with
//           all pipes <21% busy; R10 proved the reg model (VGPR+AGPR unified, 128/wave -> 4 waves/SIMD,
//           129-170 -> 3) and verified direct-from-global A-frags. B is 288KB (L2-trivial, shared);
//           A is L2-hot xs. So: NO LDS staging, NO K-loop syncthreads — both operands read straight
//           from cache per-iteration, 18 iters fully unrolled, waves drift freely. 256-thr blocks
//           (1 wave/SIMD granularity — no 2-wave rounding cliff), tile 64x256 = one image row
//           (y-neighbors wave-uniform). launch_bounds(256,3): cap 170, spill-proof. LDS ~17KB
//           (tc + epilogue zbuf only). Epilogue = R5's proven zbuf/butterfly, 16-row chunks,
//           col=(1+n)&255 zero-row-255 trick (R10-verified).

#define CLAMP63(v) ((v) < 0 ? 0 : ((v) > 63 ? 63 : (v)))

typedef __attribute__((ext_vector_type(8))) short short8;   // 8 bf16 = 4 VGPRs
typedef __attribute__((ext_vector_type(4))) float floatx4;  // C/D frag

// ---- prep: x spatial -> bf16 pixel-major [pix][64] (16B stores); col0 -> tsq = t^2
__global__ void prep_x(const float* __restrict__ x, __hip_bfloat16* __restrict__ xs,
                       float* __restrict__ tsq) {
  int idx = blockIdx.x * 256 + threadIdx.x;   // 1048576 = 131072 pix * 8 groups
  int p = idx >> 3, g = idx & 7;
  const float* src = x + (size_t)p * 65 + 1 + g * 8;
  __align__(16) __hip_bfloat16 tmp[8];
#pragma unroll
  for (int i = 0; i < 8; ++i) tmp[i] = __float2bfloat16(src[i]);
  *(short8*)(xs + (size_t)idx * 8) = *(const short8*)tmp;
  if (g == 0) { float t = x[(size_t)p * 65]; tsq[p] = t * t; }  // same cacheline as cols 1..8
}

// ---- prep: W spatial cols -> bf16 n-major [256][576] (row 255 zero); W col0 + b -> fp32 padded
__global__ void prep_w(const float* __restrict__ W, const float* __restrict__ b,
                       __hip_bfloat16* __restrict__ Wb, float* __restrict__ Wt0,
                       float* __restrict__ bp) {
  int n = blockIdx.x;  // 256
  for (int k = threadIdx.x; k < 576; k += 256)
    Wb[n * 576 + k] = __float2bfloat16((n < 255) ? W[n * 577 + 1 + k] : 0.f);
  if (threadIdx.x == 0) {
    Wt0[n] = (n < 255) ? W[n * 577] : 0.f;
    bp[n]  = (n < 255) ? b[n] : 0.f;
  }
}

// ---- main: M=64 x N=256 per block (one image row), BK=32, 18 iters, 4 waves (each 64x64).
// No K-loop barriers. A-frags: xs[row(y2)][x2][k] direct; B-frags: Wb[n][k] direct (imm offsets).
__launch_bounds__(256, 3)
__global__ void hypconv_main(const float* __restrict__ tsq,
                             const __hip_bfloat16* __restrict__ xs,
                             const __hip_bfloat16* __restrict__ Wb,
                             const float* __restrict__ Wt0,
                             const float* __restrict__ bp,
                             float* __restrict__ out) {
  __shared__ float tc_lds[64];
  __shared__ __align__(16) float zbuf[16 * 260];  // 16 rows x 260 f32 = 16640 B

  const int tid = threadIdx.x;
  const int w = tid >> 6, lane = tid & 63;
  const int quad = lane >> 4, ln = lane & 15;

  // XCD swizzle: 2048 blocks, 256-chunk per XCD (bijective); neighbor rows + Wb share an L2
  const int mb = ((blockIdx.x & 7) << 8) + (blockIdx.x >> 3);
  const int pix_base = mb * 64;
  const int bb = mb >> 6;          // image index (64 row-blocks per image)
  const int a_by = mb & 63;        // this block's image row
  const int n_off = w * 64;        // wave's n-quarter (all waves share the 64 pixels)

  // A row bases for dy = -1,0,+1 (clamped; block-uniform)
  const __hip_bfloat16* rowp[3];
#pragma unroll
  for (int d = 0; d < 3; ++d)
    rowp[d] = xs + (size_t)((bb * 64 + CLAMP63(a_by + d - 1)) * 64) * 64;

  // B fragment bases per nf (quad baked in); per-iter k advance is an immediate (it*64B <= 1088B)
  const __hip_bfloat16* bptr[4];
#pragma unroll
  for (int nf = 0; nf < 4; ++nf)
    bptr[nf] = Wb + (size_t)(n_off + nf * 16 + ln) * 576 + quad * 8;

  floatx4 acc[4][4];
#pragma unroll
  for (int mf = 0; mf < 4; ++mf)
#pragma unroll
    for (int nf = 0; nf < 4; ++nf)
      acc[mf][nf] = (floatx4){0.f, 0.f, 0.f, 0.f};

  // t_cat from tsq (512 KB, L2-resident); consumed after the post-K-loop barrier
  if (tid < 64) {
    float s = 0.f;
#pragma unroll
    for (int dy = -1; dy <= 1; ++dy) {
      int y2 = CLAMP63(a_by + dy);
#pragma unroll
      for (int dx = -1; dx <= 1; ++dx) {
        int x2 = CLAMP63(tid + dx);
        s += tsq[(bb * 64 + y2) * 64 + x2];
      }
    }
    tc_lds[tid] = sqrtf(s - 8.0f);
  }

  // ---- K-loop: 18 x BK=32, fully unrolled, ZERO barriers. k = nbr*64 + (it&1)*32 channel order.
#pragma unroll
  for (int it = 0; it < 18; ++it) {
    const int nbr = it >> 1;
    const int dyi = nbr / 3, dxi = nbr % 3;           // compile-time after unroll
    const int kofs = (it & 1) * 32 + quad * 8;        // channel slice of this frag
    short8 af[4], bfr[4];
#pragma unroll
    for (int mf = 0; mf < 4; ++mf) {
      const int x2 = CLAMP63(mf * 16 + ln + dxi - 1); // per-lane clamped x
      af[mf] = *(const short8*)(rowp[dyi] + x2 * 64 + kofs);
    }
#pragma unroll
    for (int nf = 0; nf < 4; ++nf)
      bfr[nf] = *(const short8*)(bptr[nf] + it * 32);
#pragma unroll
    for (int mf = 0; mf < 4; ++mf)
#pragma unroll
      for (int nf = 0; nf < 4; ++nf)
        acc[mf][nf] = __builtin_amdgcn_mfma_f32_16x16x32_bf16(af[mf], bfr[nf], acc[mf][nf], 0, 0, 0);
  }

  // ---- epilogue: z = acc + b[n] + t_cat[m]*W0[n]; zbuf 16 rows x 260 (conflict-free, R5-proven),
  // col = (1+n)&255 (row 255 of Wb is zero -> col 0 holds 0); t_out overwrites col 0 at flush.
  __syncthreads();   // tc_lds ready; all waves done with K
  float wn[4], bnv[4];
#pragma unroll
  for (int nf = 0; nf < 4; ++nf) {
    int n = n_off + nf * 16 + ln;
    wn[nf] = Wt0[n];
    bnv[nf] = bp[n];
  }

#pragma unroll
  for (int mf = 0; mf < 4; ++mf) {
    // stage 16 rows (this mf chunk): row lr = quad*4 + r, col = (1+n)&255
#pragma unroll
    for (int r = 0; r < 4; ++r) {
      float tcv = tc_lds[mf * 16 + quad * 4 + r];
      int lr = quad * 4 + r;
#pragma unroll
      for (int nf = 0; nf < 4; ++nf) {
        float z = acc[mf][nf][r] + bnv[nf] + tcv * wn[nf];
        zbuf[lr * 260 + ((1 + n_off + nf * 16 + ln) & 255)] = z;
      }
    }
    __syncthreads();
    // flush: 4 waves x 4 rows; sum(z^2) 64-lane butterfly; t_out -> col 0
#pragma unroll
    for (int rr = 0; rr < 4; ++rr) {
      int lr = w * 4 + rr;
      float4 v = *(const float4*)&zbuf[lr * 260 + lane * 4];
      float ss = v.x * v.x + v.y * v.y + v.z * v.z + v.w * v.w;  // col0 holds z[255]=0
      ss += __shfl_xor(ss, 1, 64);
      ss += __shfl_xor(ss, 2, 64);
      ss += __shfl_xor(ss, 4, 64);
      ss += __shfl_xor(ss, 8, 64);
      ss += __shfl_xor(ss, 16, 64);
      ss += __shfl_xor(ss, 32, 64);
      float tout = sqrtf(1.0f + ss);
      if (lane == 0) v.x = tout;
      int m = mf * 16 + lr;
      *(float4*)&out[(size_t)(pix_base + m) * 256 + lane * 4] = v;
    }
    if (mf < 3) __syncthreads();  // protect zbuf before next chunk's staging
  }
}

extern "C" void kernel_launch(void* const* d_in, const int* in_sizes, int n_in,
                              void* d_out, int out_size, void* d_ws, size_t ws_size,
                              hipStream_t stream) {
  const float* x = (const float*)d_in[0];   // (32,64,64,65)
  const float* W = (const float*)d_in[1];   // (255,577)
  const float* b = (const float*)d_in[2];   // (255,)
  float* out = (float*)d_out;               // (32,64,64,256)
  char* ws = (char*)d_ws;

  // workspace: xs 16,777,216 | Wb 294,912 | Wt0 1K | bp 1K | tsq 524,288  (~17.6 MB)
  __hip_bfloat16* xs  = (__hip_bfloat16*)(ws);
  __hip_bfloat16* Wb  = (__hip_bfloat16*)(ws + 16777216);
  float*          Wt0 = (float*)(ws + 17072128);
  float*          bp  = (float*)(ws + 17073152);
  float*          tsq = (float*)(ws + 17074176);

  prep_x<<<4096, 256, 0, stream>>>(x, xs, tsq);
  prep_w<<<256,  256, 0, stream>>>(W, b, Wb, Wt0, bp);
  hypconv_main<<<2048, 256, 0, stream>>>(tsq, xs, Wb, Wt0, bp, out);
}

// Round 8
// 200.534 us; speedup vs baseline: 4.3081x; 1.5311x over previous
//
#include <hip/hip_runtime.h>
#include <hip/hip_bf16.h>

// HypConvHyperboloid: B=32,H=64,W=64, C_IN=65, 3x3 edge-pad conv -> HCat(577) -> Lorentz FC(255) -> time restore
// M = 131072 pixels, K = 576 (bf16 MFMA) + 1 (t_cat fp32 rank-1 in epilogue), N = 255 (pad 256)
// Round 13: COALESCED OPERAND LAYOUTS. R12 (all-direct) exposed the universal bottleneck: 64-line
//           divergent gathers (B stride 1152B, A stride 128B) — present in R5's staging too
//           (~1536 line-requests/block-iter ≈ 46us/CU of TA/L1 serialization; why every schedule
//           variant pinned all pipes <20%). This round keeps champion R5 VERBATIM (2-phase dbuf loop,
//           same LDS layouts/footprint 49664B, 0-conflict frag reads, same epilogue) and only
//           re-packs the operands so every gl2lds source is lane-contiguous 1KB:
//           xs3 [row][gk(8)][x(64)][8ch] (A staging = plane slice, 16-17 lines/instr) and
//           Wp2 [it(18)][kg(4)][n(256)][8ch] (B staging = contiguous 1KB, 16 lines/instr).
//           Line traffic 1536 -> ~390 per block-iter (3.9x). Pure layout change vs 90.5us baseline.

#define CLAMP63(v) ((v) < 0 ? 0 : ((v) > 63 ? 63 : (v)))

typedef __attribute__((ext_vector_type(8))) short short8;   // 8 bf16 = 4 VGPRs
typedef __attribute__((ext_vector_type(4))) float floatx4;  // C/D frag

__device__ __forceinline__ void gl2lds16(const void* g, void* l) {
  __builtin_amdgcn_global_load_lds(
      (const __attribute__((address_space(1))) void*)g,
      (__attribute__((address_space(3))) void*)l, 16, 0, 0);
}

// ---- prep: x -> xs3 kg-plane-major bf16 [row(2048)][gk(8)][x(64)][8], LINEAR 16B stores;
//            col0 -> tsq = t^2.  thread idx: x = idx&63, gk = (idx>>6)&7, row = idx>>9.
__global__ void prep_x(const float* __restrict__ x, __hip_bfloat16* __restrict__ xs3,
                       float* __restrict__ tsq) {
  int idx = blockIdx.x * 256 + threadIdx.x;   // 1048576
  int xc = idx & 63, gk = (idx >> 6) & 7, row = idx >> 9;
  const float* src = x + (size_t)(row * 64 + xc) * 65 + 1 + gk * 8;
  __align__(16) __hip_bfloat16 tmp[8];
#pragma unroll
  for (int i = 0; i < 8; ++i) tmp[i] = __float2bfloat16(src[i]);
  *(short8*)(xs3 + (size_t)idx * 8) = *(const short8*)tmp;   // dst linear = ((row*8+gk)*64+xc)*8
  if (gk == 0) { float t = x[(size_t)(row * 64 + xc) * 65]; tsq[row * 64 + xc] = t * t; }
}

// ---- prep: W -> Wp2 fragment-linear bf16 [it(18)][kg(4)][n(256)][8] (n=255 row zero);
//            W col0 + b -> fp32 padded
__global__ void prep_w(const float* __restrict__ W, const float* __restrict__ b,
                       __hip_bfloat16* __restrict__ Wp2, float* __restrict__ Wt0,
                       float* __restrict__ bp) {
  int n = blockIdx.x;  // 256
  for (int k = threadIdx.x; k < 576; k += 256) {
    int it = k >> 5, kgl = (k >> 3) & 3, e = k & 7;
    Wp2[(((it * 4 + kgl) * 256 + n) << 3) + e] =
        __float2bfloat16((n < 255) ? W[n * 577 + 1 + k] : 0.f);
  }
  if (threadIdx.x == 0) {
    Wt0[n] = (n < 255) ? W[n * 577] : 0.f;
    bp[n]  = (n < 255) ? b[n] : 0.f;
  }
}

// staging for one iteration (A: 1 chunk/wave, B: 2 chunks/wave; all sources lane-contiguous 1KB)
#define STAGE(IT, BUF)                                                          \
  do {                                                                          \
    const int nbr_ = (IT) >> 1;                                                 \
    const int dyi_ = nbr_ / 3, dxi_ = nbr_ % 3;   /* compile-time (unrolled) */ \
    gl2lds16(arow[dyi_] + ((IT) & 1) * 2048 + xoff[dxi_],                       \
             Ab + (BUF) * 8192 + w * 1024);                                     \
    _Pragma("unroll")                                                           \
    for (int j_ = 0; j_ < 2; ++j_)                                              \
      gl2lds16(bsrc[j_] + (IT) * 8192,                                          \
               Bb + (BUF) * 16384 + (w * 2 + j_) * 1024);                       \
  } while (0)

// ---- main: M=128 x N=256 per block, BK=32, 18 iters, 8 waves (each 64x64), dbuf LDS.
// LDS A: slot = kg*128 + m (16B slots); LDS B: slot = kg*256 + n. Frag reads = R5 verbatim.
__launch_bounds__(512, 4)
__global__ void hypconv_main(const float* __restrict__ tsq,
                             const __hip_bfloat16* __restrict__ xs3,
                             const __hip_bfloat16* __restrict__ Wp2,
                             const float* __restrict__ Wt0,
                             const float* __restrict__ bp,
                             float* __restrict__ out) {
  __shared__ __align__(16) char smem[49152];  // A dbuf 16K + B dbuf 32K; reused: zbuf 32 x 260 f32
  __shared__ float tc_lds[128];
  char* Ab = smem;                            // 2 x 8192 B
  char* Bb = smem + 16384;                    // 2 x 16384 B
  float* zbuf = (float*)smem;                 // 32 rows x 260 f32 = 33280 B

  const int tid = threadIdx.x;
  const int w = tid >> 6, lane = tid & 63;
  const int quad = lane >> 4, ln = lane & 15;
  // XCD swizzle: 1024 blocks, 128-chunk per XCD (bijective)
  const int mb = ((blockIdx.x & 7) << 7) + (blockIdx.x >> 3);
  const int pix_base = mb * 128;
  const int bb = mb >> 5;                     // image index
  const int ybase = (mb & 31) << 1;           // first of the block's 2 image rows
  const int m_off = (w >> 2) * 64, n_off = (w & 3) * 64;

  // A staging (chunk w): kg = w>>1, m = (w&1)*64 + lane -> image row r = w&1, x = lane.
  // Source plane addr: ((bb*64+y2)*8 + (it&1)*4 + kg)*512 + x2*8 ; lane stride 16B (coalesced).
  const __hip_bfloat16* arow[3];
#pragma unroll
  for (int d = 0; d < 3; ++d)
    arow[d] = xs3 + ((size_t)((bb * 64 + CLAMP63(ybase + (w & 1) + d - 1)) * 8 + (w >> 1)) << 9);
  int xoff[3];
#pragma unroll
  for (int d = 0; d < 3; ++d)
    xoff[d] = CLAMP63(lane + d - 1) << 3;

  // B staging (chunks c = w*2+j): kg = c>>2, n = (c&3)*64 + lane; source lane-contiguous 1KB.
  const __hip_bfloat16* bsrc[2];
#pragma unroll
  for (int j = 0; j < 2; ++j) {
    int c = w * 2 + j;
    bsrc[j] = Wp2 + (((c >> 2) * 256 + (c & 3) * 64 + lane) << 3);
  }

  floatx4 acc[4][4];
#pragma unroll
  for (int mf = 0; mf < 4; ++mf)
#pragma unroll
    for (int nf = 0; nf < 4; ++nf)
      acc[mf][nf] = (floatx4){0.f, 0.f, 0.f, 0.f};

  STAGE(0, 0);  // prologue loads in flight

  // t_cat from tsq (512 KB, L2-resident)
  if (tid < 128) {
    int pix = pix_base + tid;
    int bx = pix & 63, by = (pix >> 6) & 63, bb2 = pix >> 12;
    float s = 0.f;
#pragma unroll
    for (int dy = -1; dy <= 1; ++dy) {
      int y2 = CLAMP63(by + dy);
#pragma unroll
      for (int dx = -1; dx <= 1; ++dx) {
        int x2 = CLAMP63(bx + dx);
        s += tsq[(bb2 * 64 + y2) * 64 + x2];
      }
    }
    tc_lds[tid] = sqrtf(s - 8.0f);
  }

#pragma unroll
  for (int it = 0; it < 18; ++it) {
    __syncthreads();                 // buf(it&1) ready; prev frag reads done
    if (it < 17) STAGE(it + 1, (it + 1) & 1);   // prefetch overlaps frag reads + MFMA
    const char* Ar = Ab + (it & 1) * 8192;
    const char* Br = Bb + (it & 1) * 16384;
    short8 af[4], bfr[4];
#pragma unroll
    for (int mf = 0; mf < 4; ++mf)
      af[mf] = *(const short8*)(Ar + (quad * 128 + m_off + mf * 16 + ln) * 16);
#pragma unroll
    for (int nf = 0; nf < 4; ++nf)
      bfr[nf] = *(const short8*)(Br + (quad * 256 + n_off + nf * 16 + ln) * 16);
#pragma unroll
    for (int mf = 0; mf < 4; ++mf)
#pragma unroll
      for (int nf = 0; nf < 4; ++nf)
        acc[mf][nf] = __builtin_amdgcn_mfma_f32_16x16x32_bf16(af[mf], bfr[nf], acc[mf][nf], 0, 0, 0);
  }

  // ---- epilogue: z = acc + b[n] + t_cat[m]*W0[n]; LDS-staged (stride 260), 1KB-row flush (R5 verbatim)
  __syncthreads();
  float wn[4], bnv[4];
#pragma unroll
  for (int nf = 0; nf < 4; ++nf) {
    int n = n_off + nf * 16 + ln;
    wn[nf] = Wt0[n];
    bnv[nf] = bp[n];
  }

#pragma unroll
  for (int mf = 0; mf < 4; ++mf) {
    // stage 32 rows: lr = (w>>2)*16 + quad*4 + r ; col = (1+n)&255 (z[255]=0 by padding)
#pragma unroll
    for (int r = 0; r < 4; ++r) {
      float tcv = tc_lds[m_off + mf * 16 + quad * 4 + r];
      int lr = (w >> 2) * 16 + quad * 4 + r;
#pragma unroll
      for (int nf = 0; nf < 4; ++nf) {
        float z = acc[mf][nf][r] + bnv[nf] + tcv * wn[nf];
        zbuf[lr * 260 + ((1 + n_off + nf * 16 + ln) & 255)] = z;
      }
    }
    __syncthreads();
    // flush: 8 waves x 4 rows; sum(z^2) 64-lane butterfly; t_out -> col 0
#pragma unroll
    for (int rr = 0; rr < 4; ++rr) {
      int lr = w * 4 + rr;
      float4 v = *(const float4*)&zbuf[lr * 260 + lane * 4];
      float ss = v.x * v.x + v.y * v.y + v.z * v.z + v.w * v.w;  // col0 holds z[255]=0
      ss += __shfl_xor(ss, 1, 64);
      ss += __shfl_xor(ss, 2, 64);
      ss += __shfl_xor(ss, 4, 64);
      ss += __shfl_xor(ss, 8, 64);
      ss += __shfl_xor(ss, 16, 64);
      ss += __shfl_xor(ss, 32, 64);
      float tout = sqrtf(1.0f + ss);
      if (lane == 0) v.x = tout;
      int m = (lr >> 4) * 64 + mf * 16 + (lr & 15);
      *(float4*)&out[(size_t)(pix_base + m) * 256 + lane * 4] = v;
    }
    if (mf < 3) __syncthreads();  // protect zbuf before next chunk's staging
  }
}

extern "C" void kernel_launch(void* const* d_in, const int* in_sizes, int n_in,
                              void* d_out, int out_size, void* d_ws, size_t ws_size,
                              hipStream_t stream) {
  const float* x = (const float*)d_in[0];   // (32,64,64,65)
  const float* W = (const float*)d_in[1];   // (255,577)
  const float* b = (const float*)d_in[2];   // (255,)
  float* out = (float*)d_out;               // (32,64,64,256)
  char* ws = (char*)d_ws;

  // workspace: xs3 16,777,216 | Wp2 294,912 | Wt0 1K | bp 1K | tsq 524,288  (~17.6 MB)
  __hip_bfloat16* xs3 = (__hip_bfloat16*)(ws);
  __hip_bfloat16* Wp2 = (__hip_bfloat16*)(ws + 16777216);
  float*          Wt0 = (float*)(ws + 17072128);
  float*          bp  = (float*)(ws + 17073152);
  float*          tsq = (float*)(ws + 17074176);

  prep_x<<<4096, 256, 0, stream>>>(x, xs3, tsq);
  prep_w<<<256,  256, 0, stream>>>(W, b, Wp2, Wt0, bp);
  hypconv_main<<<1024, 512, 0, stream>>>(tsq, xs3, Wp2, Wt0, bp, out);
}